// Round 3
// baseline (81.077 us; speedup 1.0000x reference)
//
#include <hip/hip_runtime.h>

// Problem constants (B, I, C, U, S) = (256, 8, 1152, 10, 16)
#define B_DIM 256
#define I_DIM 8
#define C_DIM 1152
#define U_DIM 10
#define S_DIM 16
#define ROWS  (B_DIM * I_DIM)   // 2048 rows of the [rows, C] view of x
#define CPB   4                 // capsules (c) per block
#define TPB   128

// Single fused kernel. Block = 128 threads, owns 4 consecutive capsules.
// Phase 1: batch-reduce x[:, :, c0:c0+4] -> xs[i][col] (block-local, x read
//          exactly once chip-wide; adjacent blocks share cache lines).
// Phase 2 (wave 0 only): u_sum via coalesced float4 W loads, then 3 routing
//          iterations fully in registers; S=16 reductions via in-wave
//          butterfly shuffles. Softmax iter 0 specialized (softmax(0)=0.1),
//          last iteration skips the unused agreement update.
__global__ __launch_bounds__(TPB) void capsule_fused_kernel(
    const float* __restrict__ x, const float* __restrict__ W,
    float* __restrict__ out) {
    __shared__ float red[2][I_DIM][CPB];   // [wave][i][col]
    __shared__ float xs_lds[I_DIM][CPB];

    const int t = threadIdx.x;
    const int lane = t & 63;
    const int wv = t >> 6;
    const int c0 = blockIdx.x * CPB;

    // ---- phase 1: accumulate rows r = t + 128k (i = t&7 is fixed per thread) ----
    float4 acc = make_float4(0.f, 0.f, 0.f, 0.f);
    const float* px = x + (size_t)t * C_DIM + c0;
#pragma unroll
    for (int k = 0; k < ROWS / TPB; ++k) {
        float4 v = *(const float4*)(px + (size_t)k * TPB * C_DIM);
        acc.x += v.x; acc.y += v.y; acc.z += v.z; acc.w += v.w;
    }
    // butterfly over lane bits 3..5: sums the 8 lanes sharing i = lane&7
#pragma unroll
    for (int m = 8; m <= 32; m <<= 1) {
        acc.x += __shfl_xor(acc.x, m);
        acc.y += __shfl_xor(acc.y, m);
        acc.z += __shfl_xor(acc.z, m);
        acc.w += __shfl_xor(acc.w, m);
    }
    if (lane < I_DIM) {
        red[wv][lane][0] = acc.x; red[wv][lane][1] = acc.y;
        red[wv][lane][2] = acc.z; red[wv][lane][3] = acc.w;
    }
    __syncthreads();
    if (t < I_DIM * CPB) {
        const int i = t >> 2, col = t & 3;
        xs_lds[i][col] = red[0][i][col] + red[1][i][col];
    }
    __syncthreads();
    if (t >= 64) return;                   // wave 1 done; routing is wave 0

    // ---- phase 2: routing, one thread per (c_local, s) ----
    const int c_local = t >> 4;            // 0..3
    const int s = t & 15;
    const int c = c0 + c_local;

    float xs[I_DIM];
#pragma unroll
    for (int i = 0; i < I_DIM; ++i) xs[i] = xs_lds[i][c_local];

    // u_sum[u] = dot(W[c,u,s,:], xs); W contiguous in i (32 B)
    float us[U_DIM];
#pragma unroll
    for (int u = 0; u < U_DIM; ++u) {
        const float4* w = (const float4*)(W + (((size_t)c * U_DIM + u) * S_DIM + s) * I_DIM);
        float4 w0 = w[0], w1 = w[1];
        us[u] = w0.x * xs[0] + w0.y * xs[1] + w0.z * xs[2] + w0.w * xs[3] +
                w1.x * xs[4] + w1.y * xs[5] + w1.z * xs[6] + w1.w * xs[7];
    }

    float bij[U_DIM];
    float v[U_DIM];

    // iteration 0: softmax(0) == 1/10 exactly
#pragma unroll
    for (int u = 0; u < U_DIM; ++u) {
        const float sj = 0.1f * us[u];
        float msq = sj * sj;
#pragma unroll
        for (int w = 1; w < 16; w <<= 1) msq += __shfl_xor(msq, w);
        const float mag = sqrtf(msq);
        const float v0 = (msq / (1.f + msq)) * (sj / mag);
        v[u] = v0;
        float a = us[u] * v0;
#pragma unroll
        for (int w = 1; w < 16; w <<= 1) a += __shfl_xor(a, w);
        bij[u] = a * (1.f / (float)B_DIM);
    }

    // iterations 1..2; last iteration skips the unused b update
#pragma unroll
    for (int it = 1; it < 3; ++it) {
        float m = bij[0];
#pragma unroll
        for (int u = 1; u < U_DIM; ++u) m = fmaxf(m, bij[u]);
        float e[U_DIM];
        float sum = 0.f;
#pragma unroll
        for (int u = 0; u < U_DIM; ++u) { e[u] = __expf(bij[u] - m); sum += e[u]; }
        const float inv = 1.f / sum;

#pragma unroll
        for (int u = 0; u < U_DIM; ++u) {
            const float sj = e[u] * inv * us[u];
            float msq = sj * sj;
#pragma unroll
            for (int w = 1; w < 16; w <<= 1) msq += __shfl_xor(msq, w);
            const float mag = sqrtf(msq);
            const float vv = (msq / (1.f + msq)) * (sj / mag);
            v[u] = vv;
            if (it < 2) {
                float a = us[u] * vv;
#pragma unroll
                for (int w = 1; w < 16; w <<= 1) a += __shfl_xor(a, w);
                bij[u] += a * (1.f / (float)B_DIM);
            }
        }
    }

#pragma unroll
    for (int u = 0; u < U_DIM; ++u)
        out[(size_t)c * (U_DIM * S_DIM) + u * S_DIM + s] = v[u];
}

extern "C" void kernel_launch(void* const* d_in, const int* in_sizes, int n_in,
                              void* d_out, int out_size, void* d_ws, size_t ws_size,
                              hipStream_t stream) {
    const float* x = (const float*)d_in[0];   // [256, 8, 1152]
    const float* W = (const float*)d_in[1];   // [1, 1152, 10, 16, 8]
    float* out = (float*)d_out;               // [1152, 10, 16]

    capsule_fused_kernel<<<C_DIM / CPB, TPB, 0, stream>>>(x, W, out);
}

// Round 4
// 73.210 us; speedup vs baseline: 1.1075x; 1.1075x over previous
//
#include <hip/hip_runtime.h>

// Problem constants (B, I, C, U, S) = (256, 8, 1152, 10, 16)
#define B_DIM 256
#define I_DIM 8
#define C_DIM 1152
#define U_DIM 10
#define S_DIM 16
#define ROWS  (B_DIM * I_DIM)   // 2048 rows of the [ROWS, C] view of x
#define CPB   16                // capsules per block -> 64 B = one full cache line per row
#define TPB   256

// Single fused kernel, 72 blocks x 256 threads.
// Phase 1: batch-reduce x[:, c0:c0+16]. Thread t owns (rgrp = t>>2, chunk = t&3);
//          it reads float4 at row (rgrp + 64k), cols c0 + 4*chunk. The 4 chunks
//          of 4 lanes cover one full 64 B line per row -> x fetched exactly once,
//          100% line utilization, 32 independent loads/thread for MLP.
//          i = row & 7 = rgrp & 7 is fixed per thread.
// Phase 2: routing, one thread per (c_local = t>>4, s = t&15); S=16 reductions
//          via in-wave butterfly shuffles; b_ij/softmax in registers.
__global__ __launch_bounds__(TPB) void capsule_fused_kernel(
    const float* __restrict__ x, const float* __restrict__ W,
    float* __restrict__ out) {
    __shared__ float4 red4[4][I_DIM][4];   // [wave][i][chunk]
    __shared__ float  xs_lds[I_DIM][CPB];  // [i][c_local]

    const int t = threadIdx.x;
    const int lane = t & 63;
    const int wv = t >> 6;
    const int c0 = blockIdx.x * CPB;

    // ---- phase 1 ----
    {
        const int rgrp = t >> 2;           // 0..63
        const int chunk = t & 3;
        const float* px = x + (size_t)rgrp * C_DIM + c0 + 4 * chunk;
        float4 acc = make_float4(0.f, 0.f, 0.f, 0.f);
#pragma unroll
        for (int k = 0; k < ROWS / 64; ++k) {          // 32 iterations
            float4 v = *(const float4*)(px + (size_t)k * 64 * C_DIM);
            acc.x += v.x; acc.y += v.y; acc.z += v.z; acc.w += v.w;
        }
        // within wave: lanes l and l^32 share (i = (lane>>2)&7, chunk)
        acc.x += __shfl_xor(acc.x, 32);
        acc.y += __shfl_xor(acc.y, 32);
        acc.z += __shfl_xor(acc.z, 32);
        acc.w += __shfl_xor(acc.w, 32);
        if (lane < 32)
            red4[wv][lane >> 2][lane & 3] = acc;
    }
    __syncthreads();
    if (t < 32) {
        const int i = t >> 2, chunk = t & 3;
        float4 a0 = red4[0][i][chunk], a1 = red4[1][i][chunk];
        float4 a2 = red4[2][i][chunk], a3 = red4[3][i][chunk];
        float4 sum = make_float4(a0.x + a1.x + a2.x + a3.x,
                                 a0.y + a1.y + a2.y + a3.y,
                                 a0.z + a1.z + a2.z + a3.z,
                                 a0.w + a1.w + a2.w + a3.w);
        *(float4*)&xs_lds[i][chunk * 4] = sum;
    }
    __syncthreads();

    // ---- phase 2: routing, 256 threads = 16 c_local x 16 s ----
    const int c_local = t >> 4;
    const int s = t & 15;
    const int c = c0 + c_local;

    float xs[I_DIM];
#pragma unroll
    for (int i = 0; i < I_DIM; ++i) xs[i] = xs_lds[i][c_local];

    // u_sum[u] = dot(W[c,u,s,:], xs); W contiguous in i (32 B/thread, 512 B/(c,u))
    float us[U_DIM];
#pragma unroll
    for (int u = 0; u < U_DIM; ++u) {
        const float4* w = (const float4*)(W + (((size_t)c * U_DIM + u) * S_DIM + s) * I_DIM);
        float4 w0 = w[0], w1 = w[1];
        us[u] = w0.x * xs[0] + w0.y * xs[1] + w0.z * xs[2] + w0.w * xs[3] +
                w1.x * xs[4] + w1.y * xs[5] + w1.z * xs[6] + w1.w * xs[7];
    }

    float bij[U_DIM];
    float v[U_DIM];

    // iteration 0: softmax(0) == 1/10 exactly
#pragma unroll
    for (int u = 0; u < U_DIM; ++u) {
        const float sj = 0.1f * us[u];
        float msq = sj * sj;
#pragma unroll
        for (int w = 1; w < 16; w <<= 1) msq += __shfl_xor(msq, w);
        const float mag = sqrtf(msq);
        const float v0 = (msq / (1.f + msq)) * (sj / mag);
        v[u] = v0;
        float a = us[u] * v0;
#pragma unroll
        for (int w = 1; w < 16; w <<= 1) a += __shfl_xor(a, w);
        bij[u] = a * (1.f / (float)B_DIM);
    }

    // iterations 1..2; last iteration skips the unused b update
#pragma unroll
    for (int it = 1; it < 3; ++it) {
        float m = bij[0];
#pragma unroll
        for (int u = 1; u < U_DIM; ++u) m = fmaxf(m, bij[u]);
        float e[U_DIM];
        float sum = 0.f;
#pragma unroll
        for (int u = 0; u < U_DIM; ++u) { e[u] = __expf(bij[u] - m); sum += e[u]; }
        const float inv = 1.f / sum;

#pragma unroll
        for (int u = 0; u < U_DIM; ++u) {
            const float sj = e[u] * inv * us[u];
            float msq = sj * sj;
#pragma unroll
            for (int w = 1; w < 16; w <<= 1) msq += __shfl_xor(msq, w);
            const float mag = sqrtf(msq);
            const float vv = (msq / (1.f + msq)) * (sj / mag);
            v[u] = vv;
            if (it < 2) {
                float a = us[u] * vv;
#pragma unroll
                for (int w = 1; w < 16; w <<= 1) a += __shfl_xor(a, w);
                bij[u] += a * (1.f / (float)B_DIM);
            }
        }
    }

#pragma unroll
    for (int u = 0; u < U_DIM; ++u)
        out[(size_t)c * (U_DIM * S_DIM) + u * S_DIM + s] = v[u];
}

extern "C" void kernel_launch(void* const* d_in, const int* in_sizes, int n_in,
                              void* d_out, int out_size, void* d_ws, size_t ws_size,
                              hipStream_t stream) {
    const float* x = (const float*)d_in[0];   // [256, 8, 1152]
    const float* W = (const float*)d_in[1];   // [1, 1152, 10, 16, 8]
    float* out = (float*)d_out;               // [1152, 10, 16]

    capsule_fused_kernel<<<C_DIM / CPB, TPB, 0, stream>>>(x, W, out);
}